// Round 4
// baseline (370.749 us; speedup 1.0000x reference)
//
#include <hip/hip_runtime.h>
#include <hip/hip_bf16.h>
#include <stdint.h>

#define N_TOT    131072
#define DIM      256
#define KCODES   1024
#define THW      16384        // 16*32*32
#define OUT_ELEMS 33554432ULL // 8*256*16*32*32

typedef short short8 __attribute__((ext_vector_type(8)));
typedef float f32x4  __attribute__((ext_vector_type(4)));

__device__ __forceinline__ unsigned short f2bf_rne(float f) {
  union { float f; unsigned int u; } c; c.f = f;
  unsigned int u = c.u;
  unsigned int r = u + 0x7FFFu + ((u >> 16) & 1u);
  return (unsigned short)(r >> 16);
}

__device__ __forceinline__ void async_cp16(void* lds, const void* gsrc) {
  __builtin_amdgcn_global_load_lds(
      (const __attribute__((address_space(1))) void*)gsrc,
      (__attribute__((address_space(3))) void*)lds, 16, 0, 0);
}

// ---------------- prep: embB in MFMA B-FRAGMENT ORDER (bf16), e2 ----------
// Fragment order: for codeword k, channel c:
//   cg = k>>4, l15 = k&15, ks = c>>5, q = (c>>3)&3, j = c&7, lane = q*16+l15
//   ushort index = ((cg*8 + ks)*64 + lane)*8 + j
// => a wave's ds_read_b128 at ((cg*8+ks)*64 + lane)*16 B is LINEAR (0 conflicts),
//    and global->LDS staging is a straight linear memcpy.
__global__ __launch_bounds__(64) void k_prep(const float* __restrict__ emb,
                                             unsigned short* __restrict__ embB,
                                             float* __restrict__ e2) {
  const int k = blockIdx.x;
  const int t = threadIdx.x;
  const float4 v = ((const float4*)(emb + (size_t)k * DIM))[t];   // c = 4t..4t+3
  float s = v.x * v.x + v.y * v.y + v.z * v.z + v.w * v.w;
  ushort4 bv;
  bv.x = f2bf_rne(v.x); bv.y = f2bf_rne(v.y);
  bv.z = f2bf_rne(v.z); bv.w = f2bf_rne(v.w);
  const int c0 = 4 * t;
  const int ks = c0 >> 5, q = (c0 >> 3) & 3, j0 = c0 & 7;
  const int lane = q * 16 + (k & 15);
  unsigned short* dst = embB + (size_t)((((k >> 4) * 8 + ks) * 64 + lane) * 8 + j0);
  *(ushort4*)dst = bv;
  #pragma unroll
  for (int m = 32; m; m >>= 1) s += __shfl_xor(s, m, 64);
  if (t == 0) e2[k] = s;
}

// ---------------- main: fused distance-GEMM + argmin + loss partials ----------------
// R4 OCCUPANCY FIX: gemm & k_out both ran at ~7x their throughput floors with the
// shared trait "64KB LDS -> 2 blocks/CU -> 2 waves/SIMD". Chunk shrunk 32KB->16KB
// (32 codewords), e2 moved into LDS => 36.9 KB/block => 3-4 blocks/CU = 12-16
// waves/CU (1.5-2x). Grid 1024 x 256 thr (4 waves x 32 rows, 2 A-frags = R0's
// proven no-spill register shape, VGPR ~160 with PLAIN __launch_bounds__ — any
// min-waves hint hard-caps VGPRs and spills A to scratch, R1/R2 lesson).
// Loss: wave shfl-sum -> block LDS sum -> one plain store (no atomics).
// Argmin packed: 10-bit codeword index in low mantissa bits, v_min_f32 only
// (near-tie misselection bounded by codeword diameter = measured absmax 0.00195).
__global__ __launch_bounds__(256) void k_gemm_argmin(
    const float* __restrict__ x, const unsigned short* __restrict__ embB,
    const float* __restrict__ e2, int* __restrict__ idxOut,
    float* __restrict__ lossPart) {
  __shared__ __align__(16) unsigned short eT[2][8192];   // 2 x 16 KB (32 codewords)
  __shared__ __align__(16) float e2l[KCODES];            // 4 KB
  __shared__ float red[4];

  const int tid  = threadIdx.x;
  const int wave = tid >> 6;
  const int lane = tid & 63;
  const int q    = lane >> 4;     // quad 0..3
  const int l15  = lane & 15;
  const int nw0  = blockIdx.x * 128 + wave * 32;   // wave's first row (32 rows/wave)
  const int b    = nw0 >> 14;                      // batch idx (uniform: 16384 % 128 == 0)

  // ---- stage e2 (4 KB) + chunk 0 (16 KB) while we build A ----
  async_cp16((char*)e2l + tid * 16, (const char*)e2 + tid * 16);
  {
    const char* gsrc = (const char*)embB;
    char* ldst = (char*)&eT[0][0];
    #pragma unroll
    for (int kk = 0; kk < 4; ++kk)
      async_cp16(ldst + (tid + kk * 256) * 16, gsrc + (size_t)(tid + kk * 256) * 16);
  }

  // ---- A fragments: 32 rows x 256 c, bf16(-2x), register-resident (64 VGPR) ----
  // A-operand layout (verified R1): lane holds A[m = l15][k = q*8 + j], j=0..7.
  short8 A[2][8];
  float x2sum = 0.0f;
  #pragma unroll
  for (int mf = 0; mf < 2; ++mf) {
    const int n   = nw0 + mf * 16 + l15;
    const int thw = n & (THW - 1);
    const float* __restrict__ xr = x + (size_t)b * DIM * THW + thw;
    #pragma unroll
    for (int ks = 0; ks < 8; ++ks) {
      const int c0 = ks * 32 + q * 8;
      short8 a;
      #pragma unroll
      for (int j = 0; j < 8; ++j) {
        float v = xr[(size_t)(c0 + j) * THW];
        x2sum += v * v;
        a[j] = (short)f2bf_rne(-2.0f * v);
      }
      A[mf][ks] = a;
    }
  }

  // packed running min: distance key with codeword index in low 10 bits
  float pmin[2][4];
  #pragma unroll
  for (int mf = 0; mf < 2; ++mf)
    #pragma unroll
    for (int r = 0; r < 4; ++r) pmin[mf][r] = 3.4e38f;

  __syncthreads();   // e2 + chunk 0 staged

  // ---- 32 chunks x 32 codewords; prefetch next, consume current, 1 barrier ----
  for (int ch = 0; ch < 32; ++ch) {
    if (ch + 1 < 32) {
      const char* gsrc = (const char*)embB + (size_t)(ch + 1) * 16384;
      char* ldst = (char*)&eT[(ch + 1) & 1][0];
      #pragma unroll
      for (int kk = 0; kk < 4; ++kk)
        async_cp16(ldst + (tid + kk * 256) * 16, gsrc + (size_t)(tid + kk * 256) * 16);
    }
    const unsigned short* __restrict__ buf = &eT[ch & 1][0];
    const int cb = ch * 32;

    #pragma unroll
    for (int cgl = 0; cgl < 2; ++cgl) {
      // B-operand: lane holds B[k = q*8+j][n = l15]; fragment-order => linear reads
      short8 B[8];
      #pragma unroll
      for (int ks = 0; ks < 8; ++ks)
        B[ks] = *(const short8*)(buf + (size_t)(((cgl * 8 + ks) * 64 + lane) * 8));
      const int   cod = cb + cgl * 16 + l15;
      const float e2v = e2l[cod];                 // LDS, broadcast across quads

      f32x4 acc0 = {0.f, 0.f, 0.f, 0.f};
      f32x4 acc1 = {0.f, 0.f, 0.f, 0.f};
      #pragma unroll
      for (int ks = 0; ks < 8; ++ks) {
        acc0 = __builtin_amdgcn_mfma_f32_16x16x32_bf16(A[0][ks], B[ks], acc0, 0, 0, 0);
        acc1 = __builtin_amdgcn_mfma_f32_16x16x32_bf16(A[1][ks], B[ks], acc1, 0, 0, 0);
      }
      // D layout (verified R1): row = q*4 + r, col = l15 (codeword)
      const unsigned int codu = (unsigned int)cod;
      #pragma unroll
      for (int r = 0; r < 4; ++r) {
        float d0 = acc0[r] + e2v;
        unsigned int u0 = (__float_as_uint(d0) & 0xFFFFFC00u) | codu;
        pmin[0][r] = fminf(pmin[0][r], __uint_as_float(u0));
        float d1 = acc1[r] + e2v;
        unsigned int u1 = (__float_as_uint(d1) & 0xFFFFFC00u) | codu;
        pmin[1][r] = fminf(pmin[1][r], __uint_as_float(u1));
      }
    }
    __syncthreads();   // prefetch landed (flew over ~64 MFMAs) + buf-reuse guard
  }

  // ---- reduce argmin across the 16 lanes (cols) holding the same rows ----
  #pragma unroll
  for (int m = 1; m <= 8; m <<= 1)
    #pragma unroll
    for (int mf = 0; mf < 2; ++mf)
      #pragma unroll
      for (int r = 0; r < 4; ++r)
        pmin[mf][r] = fminf(pmin[mf][r], __shfl_xor(pmin[mf][r], m, 64));

  float sstar = 0.0f;
  if (l15 == 0) {
    #pragma unroll
    for (int mf = 0; mf < 2; ++mf)
      #pragma unroll
      for (int r = 0; r < 4; ++r) {
        const unsigned int u = __float_as_uint(pmin[mf][r]);
        idxOut[nw0 + mf * 16 + q * 4 + r] = (int)(u & 1023u);
        sstar += __uint_as_float(u & 0xFFFFFC00u);
      }
  }
  // ---- loss: wave shfl-sum -> per-block LDS sum -> ONE plain store (no atomics) ----
  float tot = x2sum + sstar;
  #pragma unroll
  for (int m = 32; m; m >>= 1) tot += __shfl_xor(tot, m, 64);
  if (lane == 0) red[wave] = tot;
  __syncthreads();
  if (tid == 0) lossPart[blockIdx.x] = red[0] + red[1] + red[2] + red[3];
}

// ---------------- epilogue: gather + LDS transpose + float4 coalesced stores --------
// 512 blocks x 256 thr; block = 256 rows x 256 c, c in 8 chunks of 32.
// R4: tile shrunk to [256][33] = 33.8 KB -> 4 blocks/CU = 16 waves/CU (was 2 blocks
// at 66.5 KB). Same verified indexing, TSTR 65->33, chunk width 64->32.
// Stores are 16 B/lane, 1 KB/wave-inst, fully coalesced. HBM-write-bound by design.
// Block 0 / wave 0 additionally sums the 1024 gemm loss partials (stream order
// guarantees gemm is done) and writes the loss scalar — no sync, no atomics.
#define TSTR 33
__global__ __launch_bounds__(256) void k_out(
    const float* __restrict__ emb, const int* __restrict__ idx,
    float* __restrict__ out, const float* __restrict__ lossPart) {
  __shared__ __align__(16) float tile[256 * TSTR];   // 33792 B
  const int tid  = threadIdx.x;
  const int wave = tid >> 6;
  const int lane = tid & 63;
  const int l15  = lane & 15;
  const int n0   = blockIdx.x * 256;

  if (blockIdx.x == 0 && tid < 64) {
    float s = 0.0f;
    #pragma unroll
    for (int i = 0; i < 16; ++i) s += lossPart[tid + i * 64];
    #pragma unroll
    for (int m = 32; m; m >>= 1) s += __shfl_xor(s, m, 64);
    if (tid == 0) out[OUT_ELEMS] = 1.25f * s * (1.0f / (float)OUT_ELEMS);
  }

  const int myid = idx[n0 + tid];                  // this thread's row id
  const int b    = n0 >> 14;                       // uniform (16384 % 256 == 0)
  const int thw0 = n0 & (THW - 1);
  float* __restrict__ ob = out + (size_t)b * DIM * THW + thw0;
  const float* __restrict__ er = emb + (size_t)myid * DIM;

  for (int cc = 0; cc < 8; ++cc) {
    const int c0 = cc * 32;
    // gather: thread t fills tile row t with emb[myid][c0..c0+31]
    #pragma unroll
    for (int j = 0; j < 8; ++j) {
      const float4 v = *(const float4*)(er + c0 + 4 * j);
      *(float4*)&tile[tid * TSTR + 4 * j] = v;
    }
    __syncthreads();
    // store: wave w covers n = w*64 .. w*64+63; lane: n = w*64 + 4*l15, c = c0+(l>>4)+4*ci
    #pragma unroll
    for (int ci = 0; ci < 8; ++ci) {
      const int dc = (lane >> 4) + 4 * ci;
      const int nl = wave * 64 + 4 * l15;
      float4 v;
      v.x = tile[(nl + 0) * TSTR + dc];
      v.y = tile[(nl + 1) * TSTR + dc];
      v.z = tile[(nl + 2) * TSTR + dc];
      v.w = tile[(nl + 3) * TSTR + dc];
      *(float4*)(ob + (size_t)(c0 + dc) * THW + nl) = v;
    }
    __syncthreads();   // before next chunk's gather overwrites tile
  }
}

extern "C" void kernel_launch(void* const* d_in, const int* in_sizes, int n_in,
                              void* d_out, int out_size, void* d_ws, size_t ws_size,
                              hipStream_t stream) {
  const float* x   = (const float*)d_in[0];
  const float* emb = (const float*)d_in[1];
  float* out = (float*)d_out;
  char* ws = (char*)d_ws;

  // workspace layout (16B aligned), total ~1.06 MB
  unsigned short* embB = (unsigned short*)(ws);          // 1024*256*2 = 524288 B (frag order)
  float* e2      = (float*)(ws + 524288);                // 4096 B
  int*   idx     = (int*)(ws + 528384);                  // 131072*4 = 524288 B
  float* lossPart = (float*)(ws + 1052672);              // 1024*4 = 4096 B

  k_prep<<<KCODES, 64, 0, stream>>>(emb, embB, e2);
  k_gemm_argmin<<<N_TOT / 128, 256, 0, stream>>>(x, embB, e2, idx, lossPart);
  k_out<<<N_TOT / 256, 256, 0, stream>>>(emb, idx, out, lossPart);
}

// Round 5
// 329.887 us; speedup vs baseline: 1.1239x; 1.1239x over previous
//
#include <hip/hip_runtime.h>
#include <hip/hip_bf16.h>
#include <stdint.h>

#define N_TOT    131072
#define DIM      256
#define KCODES   1024
#define THW      16384        // 16*32*32
#define OUT_ELEMS 33554432ULL // 8*256*16*32*32

typedef short short8 __attribute__((ext_vector_type(8)));
typedef float f32x4  __attribute__((ext_vector_type(4)));

__device__ __forceinline__ unsigned short f2bf_rne(float f) {
  union { float f; unsigned int u; } c; c.f = f;
  unsigned int u = c.u;
  unsigned int r = u + 0x7FFFu + ((u >> 16) & 1u);
  return (unsigned short)(r >> 16);
}

__device__ __forceinline__ void async_cp16(void* lds, const void* gsrc) {
  __builtin_amdgcn_global_load_lds(
      (const __attribute__((address_space(1))) void*)gsrc,
      (__attribute__((address_space(3))) void*)lds, 16, 0, 0);
}

// ---------------- prep: embB in MFMA B-FRAGMENT ORDER (bf16), e2 ----------
// For codeword k, channel c: cg=k>>4, l15=k&15, ks=c>>5, q=(c>>3)&3, j=c&7,
// lane=q*16+l15; ushort index = ((cg*8+ks)*64+lane)*8+j  => wave ds_read_b128 linear.
__global__ __launch_bounds__(64) void k_prep(const float* __restrict__ emb,
                                             unsigned short* __restrict__ embB,
                                             float* __restrict__ e2) {
  const int k = blockIdx.x;
  const int t = threadIdx.x;
  const float4 v = ((const float4*)(emb + (size_t)k * DIM))[t];   // c = 4t..4t+3
  float s = v.x * v.x + v.y * v.y + v.z * v.z + v.w * v.w;
  ushort4 bv;
  bv.x = f2bf_rne(v.x); bv.y = f2bf_rne(v.y);
  bv.z = f2bf_rne(v.z); bv.w = f2bf_rne(v.w);
  const int c0 = 4 * t;
  const int ks = c0 >> 5, q = (c0 >> 3) & 3, j0 = c0 & 7;
  const int lane = q * 16 + (k & 15);
  unsigned short* dst = embB + (size_t)((((k >> 4) * 8 + ks) * 64 + lane) * 8 + j0);
  *(ushort4*)dst = bv;
  #pragma unroll
  for (int m = 32; m; m >>= 1) s += __shfl_xor(s, m, 64);
  if (t == 0) e2[k] = s;
}

// ---------------- xprep: coalesced transpose x -> xf (bf16 * -2), + sum(x^2) -------
// R5 RATIONALE: gemm's in-kernel A-build was 128 scattered 4B loads/thread (64KB
// stride) — latency*queue-bound at ~170us (the entire unexplained gemm wall).
// This kernel does the layout change with 1KB-contiguous wave reads (m13-proven
// full-BW pattern) and 2KB-contiguous writes.
// xf layout, 16B units: unit(n, o=c>>3) at index (tile*32 + o)*256 + nn,
//   tile = n>>8, nn = n&255; unit bytes = bf16(-2*x[n][c]) for c = o*8..o*8+7.
// Block: 1024 thr = 16 waves, rows n0..n0+255 (one batch b), channels in 4 quarters.
__global__ __launch_bounds__(1024) void k_xprep(const float* __restrict__ x,
                                                unsigned short* __restrict__ xf,
                                                float* __restrict__ lossPartX) {
  __shared__ __align__(16) unsigned short sm[64 * 264];   // [cc][nn], 264-stride: 33 KB
  __shared__ float xred[16];
  const int tid  = threadIdx.x;
  const int w    = tid >> 6;
  const int l    = tid & 63;
  const int n0   = blockIdx.x << 8;
  const int b    = n0 >> 14;            // uniform (16384 % 256 == 0)
  const int thw0 = n0 & (THW - 1);
  const float* __restrict__ xb = x + (size_t)b * DIM * THW;
  float x2 = 0.0f;

  for (int q4 = 0; q4 < 4; ++q4) {
    // read: wave w owns planes c = q4*64 + w*4 + i; lane reads float4 at thw0+4l
    // -> 64 lanes x 16B = 1KB contiguous per instruction.
    ushort4 bv[4];
    #pragma unroll
    for (int i = 0; i < 4; ++i) {
      const int c = q4 * 64 + w * 4 + i;
      const float4 v = *(const float4*)(xb + (size_t)c * THW + thw0 + 4 * l);
      x2 += v.x * v.x + v.y * v.y + v.z * v.z + v.w * v.w;
      bv[i].x = f2bf_rne(-2.0f * v.x); bv[i].y = f2bf_rne(-2.0f * v.y);
      bv[i].z = f2bf_rne(-2.0f * v.z); bv[i].w = f2bf_rne(-2.0f * v.w);
    }
    if (q4) __syncthreads();            // prev quarter's sm reads done
    #pragma unroll
    for (int i = 0; i < 4; ++i) {       // 8B ds_write, lanes contiguous: conflict-free
      const int cc = w * 4 + i;
      *(ushort4*)&sm[cc * 264 + 4 * l] = bv[i];
    }
    __syncthreads();
    // write: thread -> units u = 2*tid, 2*tid+1 (same octet oo, nn pair 2*t2, 2*t2+1)
    const int oo = tid >> 7;            // 0..7
    const int t2 = tid & 127;
    unsigned int r[8];
    #pragma unroll
    for (int j = 0; j < 8; ++j)         // b32 reads, lanes contiguous: conflict-free
      r[j] = *(const unsigned int*)&sm[(oo * 8 + j) * 264 + 2 * t2];
    uint4 u0, u1;
    u0.x = (r[0] & 0xFFFFu) | (r[1] << 16);  u1.x = (r[0] >> 16) | (r[1] & 0xFFFF0000u);
    u0.y = (r[2] & 0xFFFFu) | (r[3] << 16);  u1.y = (r[2] >> 16) | (r[3] & 0xFFFF0000u);
    u0.z = (r[4] & 0xFFFFu) | (r[5] << 16);  u1.z = (r[4] >> 16) | (r[5] & 0xFFFF0000u);
    u0.w = (r[6] & 0xFFFFu) | (r[7] << 16);  u1.w = (r[6] >> 16) | (r[7] & 0xFFFF0000u);
    const size_t ui = ((size_t)blockIdx.x * 32 + (size_t)(q4 * 8 + oo)) * 256 + 2 * t2;
    ((uint4*)xf)[ui]     = u0;          // 32B/thread, lanes contiguous -> 2KB/instr
    ((uint4*)xf)[ui + 1] = u1;
  }
  // sum(x^2) partial for the loss (gemm no longer touches x)
  #pragma unroll
  for (int m = 32; m; m >>= 1) x2 += __shfl_xor(x2, m, 64);
  if (l == 0) xred[w] = x2;
  __syncthreads();
  if (tid == 0) {
    float s = 0.0f;
    #pragma unroll
    for (int i = 0; i < 16; ++i) s += xred[i];
    lossPartX[blockIdx.x] = s;
  }
}

// ---------------- main: distance-GEMM + argmin (A pre-transposed by k_xprep) -------
// 1024 blocks x 256 thr (4 waves x 32 rows). A: 16 dwordx4 loads/thread from xf
// (256B-coalesced groups) instead of 128 scattered dwords — the R5 fix.
// B streamed through LDS: 32 chunks x 32 codewords (16KB), double-buffered.
// Plain __launch_bounds__ (min-waves hints spill, R1/R2). Packed argmin (index in
// low 10 mantissa bits, v_min_f32 only). Loss: block partial -> plain store.
__global__ __launch_bounds__(256) void k_gemm_argmin(
    const unsigned short* __restrict__ xf, const unsigned short* __restrict__ embB,
    const float* __restrict__ e2, int* __restrict__ idxOut,
    float* __restrict__ lossPart) {
  __shared__ __align__(16) unsigned short eT[2][8192];   // 2 x 16 KB
  __shared__ __align__(16) float e2l[KCODES];            // 4 KB
  __shared__ float red[4];

  const int tid  = threadIdx.x;
  const int wave = tid >> 6;
  const int lane = tid & 63;
  const int q    = lane >> 4;
  const int l15  = lane & 15;
  const int nw0  = blockIdx.x * 128 + wave * 32;

  // ---- stage e2 (4 KB) + chunk 0 (16 KB) while A loads fly ----
  async_cp16((char*)e2l + tid * 16, (const char*)e2 + tid * 16);
  {
    const char* gsrc = (const char*)embB;
    char* ldst = (char*)&eT[0][0];
    #pragma unroll
    for (int kk = 0; kk < 4; ++kk)
      async_cp16(ldst + (tid + kk * 256) * 16, gsrc + (size_t)(tid + kk * 256) * 16);
  }

  // ---- A fragments from xf: 16 x 16B loads, verified layout lane=(q,l15) ----
  const int tile = nw0 >> 8;
  const int nnb  = nw0 & 255;
  short8 A[2][8];
  #pragma unroll
  for (int mf = 0; mf < 2; ++mf)
    #pragma unroll
    for (int ks = 0; ks < 8; ++ks)
      A[mf][ks] = *(const short8*)(xf +
          (((size_t)tile * 32 + (size_t)(ks * 4 + q)) * 256 + nnb + mf * 16 + l15) * 8);

  float pmin[2][4];
  #pragma unroll
  for (int mf = 0; mf < 2; ++mf)
    #pragma unroll
    for (int r = 0; r < 4; ++r) pmin[mf][r] = 3.4e38f;

  __syncthreads();   // e2 + chunk 0 staged

  for (int ch = 0; ch < 32; ++ch) {
    if (ch + 1 < 32) {
      const char* gsrc = (const char*)embB + (size_t)(ch + 1) * 16384;
      char* ldst = (char*)&eT[(ch + 1) & 1][0];
      #pragma unroll
      for (int kk = 0; kk < 4; ++kk)
        async_cp16(ldst + (tid + kk * 256) * 16, gsrc + (size_t)(tid + kk * 256) * 16);
    }
    const unsigned short* __restrict__ buf = &eT[ch & 1][0];
    const int cb = ch * 32;

    #pragma unroll
    for (int cgl = 0; cgl < 2; ++cgl) {
      const int   cod = cb + cgl * 16 + l15;
      const float e2v = e2l[cod];
      f32x4 acc0 = {0.f, 0.f, 0.f, 0.f};
      f32x4 acc1 = {0.f, 0.f, 0.f, 0.f};
      // B loaded per-ks (keeps VGPR pressure low; target <=128 for 16 waves/CU)
      #pragma unroll
      for (int ks = 0; ks < 8; ++ks) {
        const short8 Bk = *(const short8*)(buf + (size_t)(((cgl * 8 + ks) * 64 + lane) * 8));
        acc0 = __builtin_amdgcn_mfma_f32_16x16x32_bf16(A[0][ks], Bk, acc0, 0, 0, 0);
        acc1 = __builtin_amdgcn_mfma_f32_16x16x32_bf16(A[1][ks], Bk, acc1, 0, 0, 0);
      }
      const unsigned int codu = (unsigned int)cod;
      #pragma unroll
      for (int r = 0; r < 4; ++r) {
        float d0 = acc0[r] + e2v;
        unsigned int u0 = (__float_as_uint(d0) & 0xFFFFFC00u) | codu;
        pmin[0][r] = fminf(pmin[0][r], __uint_as_float(u0));
        float d1 = acc1[r] + e2v;
        unsigned int u1 = (__float_as_uint(d1) & 0xFFFFFC00u) | codu;
        pmin[1][r] = fminf(pmin[1][r], __uint_as_float(u1));
      }
    }
    __syncthreads();
  }

  #pragma unroll
  for (int m = 1; m <= 8; m <<= 1)
    #pragma unroll
    for (int mf = 0; mf < 2; ++mf)
      #pragma unroll
      for (int r = 0; r < 4; ++r)
        pmin[mf][r] = fminf(pmin[mf][r], __shfl_xor(pmin[mf][r], m, 64));

  float sstar = 0.0f;
  if (l15 == 0) {
    #pragma unroll
    for (int mf = 0; mf < 2; ++mf)
      #pragma unroll
      for (int r = 0; r < 4; ++r) {
        const unsigned int u = __float_as_uint(pmin[mf][r]);
        idxOut[nw0 + mf * 16 + q * 4 + r] = (int)(u & 1023u);
        sstar += __uint_as_float(u & 0xFFFFFC00u);
      }
  }
  float tot = sstar;   // x^2 term handled by k_xprep
  #pragma unroll
  for (int m = 32; m; m >>= 1) tot += __shfl_xor(tot, m, 64);
  if (lane == 0) red[wave] = tot;
  __syncthreads();
  if (tid == 0) lossPart[blockIdx.x] = red[0] + red[1] + red[2] + red[3];
}

// ---------------- epilogue: gather + LDS transpose + float4 coalesced stores --------
// R3-proven version (TSTR 65; R4's TSTR-33 variant regressed ~40us — reverted).
#define TSTR 65
__global__ __launch_bounds__(256) void k_out(
    const float* __restrict__ emb, const int* __restrict__ idx,
    float* __restrict__ out, const float* __restrict__ lossPart,
    const float* __restrict__ lossPartX) {
  __shared__ __align__(16) float tile[256 * TSTR];   // 66560 B
  const int tid  = threadIdx.x;
  const int wave = tid >> 6;
  const int lane = tid & 63;
  const int l15  = lane & 15;
  const int n0   = blockIdx.x * 256;

  if (blockIdx.x == 0 && tid < 64) {
    float s = 0.0f;
    #pragma unroll
    for (int i = 0; i < 16; ++i) s += lossPart[tid + i * 64];
    #pragma unroll
    for (int i = 0; i < 8; ++i) s += lossPartX[tid + i * 64];
    #pragma unroll
    for (int m = 32; m; m >>= 1) s += __shfl_xor(s, m, 64);
    if (tid == 0) out[OUT_ELEMS] = 1.25f * s * (1.0f / (float)OUT_ELEMS);
  }

  const int myid = idx[n0 + tid];
  const int b    = n0 >> 14;
  const int thw0 = n0 & (THW - 1);
  float* __restrict__ ob = out + (size_t)b * DIM * THW + thw0;
  const float* __restrict__ er = emb + (size_t)myid * DIM;

  for (int cc = 0; cc < 4; ++cc) {
    const int c0 = cc * 64;
    #pragma unroll
    for (int j = 0; j < 16; ++j) {
      const float4 v = *(const float4*)(er + c0 + 4 * j);
      *(float4*)&tile[tid * TSTR + 4 * j] = v;
    }
    __syncthreads();
    #pragma unroll
    for (int ci = 0; ci < 16; ++ci) {
      const int dc = (lane >> 4) + 4 * ci;
      const int nl = wave * 64 + 4 * l15;
      float4 v;
      v.x = tile[(nl + 0) * TSTR + dc];
      v.y = tile[(nl + 1) * TSTR + dc];
      v.z = tile[(nl + 2) * TSTR + dc];
      v.w = tile[(nl + 3) * TSTR + dc];
      *(float4*)(ob + (size_t)(c0 + dc) * THW + nl) = v;
    }
    __syncthreads();
  }
}

extern "C" void kernel_launch(void* const* d_in, const int* in_sizes, int n_in,
                              void* d_out, int out_size, void* d_ws, size_t ws_size,
                              hipStream_t stream) {
  const float* x   = (const float*)d_in[0];
  const float* emb = (const float*)d_in[1];
  float* out = (float*)d_out;
  char* ws = (char*)d_ws;

  // workspace layout (16B aligned), ~1.06 MB
  unsigned short* embB = (unsigned short*)(ws);          // 524288 B (frag order)
  float* e2       = (float*)(ws + 524288);               // 4096 B
  int*   idx      = (int*)(ws + 528384);                 // 524288 B
  float* lossPart  = (float*)(ws + 1052672);             // 1024*4 B
  float* lossPartX = (float*)(ws + 1056768);             // 512*4 B
  // xf (67 MB) lives in the out buffer: written by k_xprep, consumed by k_gemm,
  // then k_out overwrites out with the final result (stream-ordered, safe).
  unsigned short* xf = (unsigned short*)out;

  k_prep<<<KCODES, 64, 0, stream>>>(emb, embB, e2);
  k_xprep<<<N_TOT / 256, 1024, 0, stream>>>(x, xf, lossPartX);
  k_gemm_argmin<<<N_TOT / 128, 256, 0, stream>>>(xf, embB, e2, idx, lossPart);
  k_out<<<N_TOT / 256, 256, 0, stream>>>(emb, idx, out, lossPart, lossPartX);
}